// Round 7
// baseline (81.095 us; speedup 1.0000x reference)
//
#include <hip/hip_runtime.h>
#include <hip/hip_bf16.h>

#define B_ 8
#define T_ 4096
#define C_ 256
#define H_ 256
#define K_ 3
#define NC 128          // time chunks (32 t each)
#define TC 32
#define WFRAG_ELEMS (24 * 32 * 64 * 8)   // [ks][ntg][lane][j] bf16

typedef __attribute__((ext_vector_type(8))) __bf16 bf16x8;
typedef __attribute__((ext_vector_type(4))) float f32x4;

__device__ __forceinline__ float sigm(float x) { return 1.0f / (1.0f + __expf(-x)); }

__device__ __forceinline__ ushort f2bf(float f) {
    union { float f; unsigned u; } v; v.f = f;
    return (ushort)((v.u + 0x7FFFu + ((v.u >> 16) & 1u)) >> 16);
}
__device__ __forceinline__ float bf2f(ushort u) {
    union { unsigned u; float f; } v; v.u = ((unsigned)u) << 16; return v.f;
}

// Gather f_w,z_w into B-fragment-linear bf16 layout for mfma_f32_16x16x32_bf16.
// n = ntg*16 + (l&15)  (n<256 -> f[h=n], else z[h=n-256]);  kappa = ks*32 + (l>>4)*8 + j = k*256 + c.
__global__ __launch_bounds__(256) void wfrag_kernel(const float* __restrict__ fw,
                                                    const float* __restrict__ zw,
                                                    ushort* __restrict__ wfrag) {
    int idx = blockIdx.x * 256 + threadIdx.x;
    if (idx >= WFRAG_ELEMS) return;
    int j   = idx & 7;
    int l   = (idx >> 3) & 63;
    int ntg = (idx >> 9) & 31;
    int ks  = idx >> 14;
    int n = ntg * 16 + (l & 15);
    int kappa = ks * 32 + (l >> 4) * 8 + j;
    int k = kappa >> 8, c = kappa & 255;
    const float* w = (n < 256) ? fw : zw;
    int h = n & 255;
    wfrag[idx] = f2bf(w[(h * C_ + c) * K_ + k]);
}

// ---------------------------------------------------------------------------
// Fused conv (f and z) + gates + per-chunk affine scan.
// Block: 64 t rows x 256 h. 8 waves; wave wv owns h in [wv*32, wv*32+32):
//   ni 0,1 -> f cols (ntg = wv*2+ni), ni 2,3 -> z cols (ntg = 16+wv*2+ni-2).
// Two-phase epilogue (keeps LDS at 33792 B -> 4 blocks/CU): per 32-t chunk,
// sigmoid -> {a,f} LDS transpose (32x256 uint) -> 256-thread serial scan
// producing packed bf16 {A_j, P'_j} (P' excludes seam f) + contiguous summary.
// ---------------------------------------------------------------------------
template <int P>
__device__ __forceinline__ void epi_write(f32x4 (&acc)[4][4], unsigned* buf,
                                          int lr, int lg, int h0) {
#pragma unroll
    for (int m2 = 0; m2 < 2; ++m2) {
        const int mi = 2 * P + m2;
#pragma unroll
        for (int ni = 0; ni < 2; ++ni) {
            const int h = h0 + ni * 16 + lr;
#pragma unroll
            for (int r = 0; r < 4; ++r) {
                float fv = sigm(acc[mi][ni][r]);
                float av = sigm(acc[mi][ni + 2][r]) * (1.0f - fv);
                int tl = m2 * 16 + lg * 4 + r;
                buf[tl * 256 + (h ^ ((tl << 2) & 31))] =
                    (unsigned)f2bf(av) | ((unsigned)f2bf(fv) << 16);
            }
        }
    }
}

template <int P>
__device__ __forceinline__ void chunk_scan(const unsigned* buf, int b, int bx, int tid,
                                           unsigned* AP, unsigned* APl, float* fl) {
    if (tid < 256) {
        const int h = tid;
        const int chunk = bx * 2 + P;
        const int r0 = chunk * TC;
        unsigned* app = AP + ((size_t)b * T_ + r0) * H_ + h;
        unsigned u = buf[h];
        float A = bf2f((ushort)(u & 0xffff));
        float Pp = 1.0f;
        float f_prev = bf2f((ushort)(u >> 16));
        unsigned upk = (unsigned)f2bf(A) | ((unsigned)f2bf(Pp) << 16);
        app[0] = upk;
#pragma unroll 8
        for (int j = 1; j < TC; ++j) {
            u = buf[j * 256 + (h ^ ((j << 2) & 31))];
            float a = bf2f((ushort)(u & 0xffff));
            float f = bf2f((ushort)(u >> 16));
            A = fmaf(f_prev, A, a);
            Pp *= f_prev;
            f_prev = f;
            upk = (unsigned)f2bf(A) | ((unsigned)f2bf(Pp) << 16);
            app[(size_t)j * H_] = upk;
        }
        APl[((size_t)b * NC + chunk) * H_ + h] = upk;
        fl[((size_t)b * NC + chunk) * H_ + h] = f_prev;
    }
}

__global__ __launch_bounds__(512, 4) void conv_scan_kernel(const float* __restrict__ x,
                                                           const ushort* __restrict__ wfrag,
                                                           const float* __restrict__ fb,
                                                           const float* __restrict__ zb,
                                                           unsigned* __restrict__ AP,
                                                           unsigned* __restrict__ APl,
                                                           float* __restrict__ fl) {
    __shared__ __align__(16) char smem[66 * 512];   // union: xs 66x512B | buf 32x256 uint
    unsigned* buf = (unsigned*)smem;

    const int b = blockIdx.y;
    const int t0 = blockIdx.x * 64;
    const int tid = threadIdx.x;

    // Stage x[b, t0-1 .. t0+64, :] as bf16, swizzled: byte = row*512 + ((2c) ^ ((row&7)<<4))
    for (int idx = tid; idx < 66 * 64; idx += 512) {
        int row = idx >> 6;
        int c4 = (idx & 63) * 4;
        int t = t0 - 1 + row;
        float4 v = make_float4(0.f, 0.f, 0.f, 0.f);
        if (t >= 0 && t < T_) v = *(const float4*)(x + ((size_t)(b * T_ + t)) * C_ + c4);
        ushort4 w4;
        w4.x = f2bf(v.x); w4.y = f2bf(v.y); w4.z = f2bf(v.z); w4.w = f2bf(v.w);
        *(ushort4*)(smem + row * 512 + ((c4 * 2) ^ ((row & 7) << 4))) = w4;
    }
    __syncthreads();

    const int wv = tid >> 6;
    const int l  = tid & 63;
    const int lr = l & 15;
    const int lg = l >> 4;
    const int h0 = wv * 32;
    const int lgoff = lg * 16;

    f32x4 acc[4][4];
#pragma unroll
    for (int ni = 0; ni < 4; ++ni) {
        float bv = (ni < 2 ? fb : zb)[h0 + (ni & 1) * 16 + lr];
        f32x4 bvv = {bv, bv, bv, bv};
#pragma unroll
        for (int mi = 0; mi < 4; ++mi) acc[mi][ni] = bvv;
    }

    const ushort* wb = wfrag + (size_t)l * 8;

    // addr(mi,ks) = abase[mi] ^ ((ks&7)<<6); abase = row*512 + (lgoff^(rowx&48)) + (rowx&64)
#pragma unroll 1
    for (int kg = 0; kg < 3; ++kg) {
        int abase[4];
#pragma unroll
        for (int mi = 0; mi < 4; ++mi) {
            int row = mi * 16 + lr + kg;
            int rowx = (row & 7) << 4;
            abase[mi] = row * 512 + (lgoff ^ (rowx & 48)) + (rowx & 64);
        }
#pragma unroll
        for (int ksp = 0; ksp < 8; ++ksp) {
            const int ks = kg * 8 + ksp;
            bf16x8 afr[4];
#pragma unroll
            for (int mi = 0; mi < 4; ++mi)
                afr[mi] = *(const bf16x8*)(smem + (abase[mi] ^ (ksp << 6)));
#pragma unroll
            for (int ni = 0; ni < 4; ++ni) {
                const int ntg = (ni < 2) ? (wv * 2 + ni) : (16 + wv * 2 + ni - 2);
                bf16x8 bfr = *(const bf16x8*)(wb + (size_t)ks * 16384 + (size_t)ntg * 512);
#pragma unroll
                for (int mi = 0; mi < 4; ++mi)
                    acc[mi][ni] = __builtin_amdgcn_mfma_f32_16x16x32_bf16(afr[mi], bfr, acc[mi][ni], 0, 0, 0);
            }
        }
    }

    // ---- phase 0: chunk = bx*2 (mi 0,1) ----
    __syncthreads();                       // xs dead; buf aliases it
    epi_write<0>(acc, buf, lr, lg, h0);
    __syncthreads();
    chunk_scan<0>(buf, b, blockIdx.x, tid, AP, APl, fl);

    // ---- phase 1: chunk = bx*2+1 (mi 2,3) ----
    __syncthreads();
    epi_write<1>(acc, buf, lr, lg, h0);
    __syncthreads();
    chunk_scan<1>(buf, b, blockIdx.x, tid, AP, APl, fl);
}

// Per (b,h): serial over contiguous chunk summaries (coalesced, prefetchable).
// s~_c = fl(c-1)*s_c; s_{c+1} = A31 + P'31*s~_c.
__global__ __launch_bounds__(256) void combine_kernel(const unsigned* __restrict__ APl,
                                                      const float* __restrict__ fl,
                                                      const float* __restrict__ init_f,
                                                      const float* __restrict__ init_z,
                                                      float* __restrict__ out,
                                                      float* __restrict__ sin_) {
    const int b = blockIdx.x;
    const int h = threadIdx.x;
    float f0 = sigm(init_f[b * H_ + h]);
    float z0 = sigm(init_z[b * H_ + h]);
    float s = z0 * (1.0f - f0);
    out[(size_t)b * (T_ + 1) * H_ + h] = s;
    float flp = f0;
    const unsigned* ap = APl + (size_t)b * NC * H_ + h;
    const float* fp = fl + (size_t)b * NC * H_ + h;
    float* sp = sin_ + (size_t)b * NC * H_ + h;
#pragma unroll 8
    for (int c = 0; c < NC; ++c) {
        unsigned u = ap[(size_t)c * H_];
        float fln = fp[(size_t)c * H_];
        float st = flp * s;
        sp[(size_t)c * H_] = st;
        s = fmaf(bf2f((ushort)(u >> 16)), st, bf2f((ushort)(u & 0xffff)));
        flp = fln;
    }
}

// out_{r0+1+j} = A_j + P'_j * s~_c   (fully parallel, 4 h per thread)
__global__ __launch_bounds__(256) void apply_kernel(const unsigned* __restrict__ AP,
                                                    const float* __restrict__ sin_,
                                                    float* __restrict__ out) {
    const int c = blockIdx.x;
    const int b = blockIdx.y;
    const int tid = threadIdx.x;
    const int jr = tid >> 6;
    const int h4 = (tid & 63) * 4;
    const int r0 = c * TC;
    const float4 s4 = *(const float4*)(sin_ + ((size_t)b * NC + c) * H_ + h4);
#pragma unroll
    for (int p = 0; p < 8; ++p) {
        const int j = p * 4 + jr;
        const uint4 u4 = *(const uint4*)(AP + ((size_t)b * T_ + r0 + j) * H_ + h4);
        float4 o;
        o.x = fmaf(bf2f((ushort)(u4.x >> 16)), s4.x, bf2f((ushort)(u4.x & 0xffff)));
        o.y = fmaf(bf2f((ushort)(u4.y >> 16)), s4.y, bf2f((ushort)(u4.y & 0xffff)));
        o.z = fmaf(bf2f((ushort)(u4.z >> 16)), s4.z, bf2f((ushort)(u4.z & 0xffff)));
        o.w = fmaf(bf2f((ushort)(u4.w >> 16)), s4.w, bf2f((ushort)(u4.w & 0xffff)));
        *(float4*)(out + ((size_t)b * (T_ + 1) + r0 + 1 + j) * H_ + h4) = o;
    }
}

extern "C" void kernel_launch(void* const* d_in, const int* in_sizes, int n_in,
                              void* d_out, int out_size, void* d_ws, size_t ws_size,
                              hipStream_t stream) {
    const float* inputs = (const float*)d_in[0];   // [B,T,C]
    const float* init_f = (const float*)d_in[1];   // [B,H]
    const float* init_z = (const float*)d_in[2];   // [B,H]
    const float* f_w    = (const float*)d_in[3];   // [H,C,K]
    const float* f_b    = (const float*)d_in[4];   // [H]
    const float* z_w    = (const float*)d_in[5];   // [H,C,K]
    const float* z_b    = (const float*)d_in[6];   // [H]
    float* out = (float*)d_out;                    // [B,T+1,H]

    // ws: wfrag 768KB | AP (B*T*H uint, 32MB) | APl 1MB | fl 1MB | sin 1MB
    ushort* wfrag = (ushort*)d_ws;
    unsigned* AP  = (unsigned*)(wfrag + WFRAG_ELEMS);
    unsigned* APl = AP + (size_t)B_ * T_ * H_;
    float* fl     = (float*)(APl + (size_t)B_ * NC * H_);
    float* sin_   = fl + (size_t)B_ * NC * H_;

    wfrag_kernel<<<(WFRAG_ELEMS + 255) / 256, 256, 0, stream>>>(f_w, z_w, wfrag);

    dim3 cgrid(T_ / 64, B_, 1);
    conv_scan_kernel<<<cgrid, 512, 0, stream>>>(inputs, wfrag, f_b, z_b, AP, APl, fl);

    combine_kernel<<<B_, H_, 0, stream>>>(APl, fl, init_f, init_z, out, sin_);

    dim3 agrid(NC, B_, 1);
    apply_kernel<<<agrid, 256, 0, stream>>>(AP, sin_, out);
}

// Round 8
// 68.844 us; speedup vs baseline: 1.1780x; 1.1780x over previous
//
#include <hip/hip_runtime.h>
#include <hip/hip_bf16.h>

#define B_ 8
#define T_ 4096
#define C_ 256
#define H_ 256
#define K_ 3
#define NC 128          // time chunks (32 t each)
#define TC 32
#define WFRAG_ELEMS (24 * 32 * 64 * 8)   // [ks][ntg][lane][j] bf16

typedef __attribute__((ext_vector_type(8))) __bf16 bf16x8;
typedef __attribute__((ext_vector_type(4))) float f32x4;

__device__ __forceinline__ float sigm(float x) { return 1.0f / (1.0f + __expf(-x)); }

__device__ __forceinline__ ushort f2bf(float f) {
    union { float f; unsigned u; } v; v.f = f;
    return (ushort)((v.u + 0x7FFFu + ((v.u >> 16) & 1u)) >> 16);
}
__device__ __forceinline__ float bf2f(ushort u) {
    union { unsigned u; float f; } v; v.u = ((unsigned)u) << 16; return v.f;
}

// Gather f_w,z_w into B-fragment-linear bf16 layout for mfma_f32_16x16x32_bf16.
// n = ntg*16 + (l&15)  (n<256 -> f[h=n], else z[h=n-256]);  kappa = ks*32 + (l>>4)*8 + j = k*256 + c.
__global__ __launch_bounds__(256) void wfrag_kernel(const float* __restrict__ fw,
                                                    const float* __restrict__ zw,
                                                    ushort* __restrict__ wfrag) {
    int idx = blockIdx.x * 256 + threadIdx.x;
    if (idx >= WFRAG_ELEMS) return;
    int j   = idx & 7;
    int l   = (idx >> 3) & 63;
    int ntg = (idx >> 9) & 31;
    int ks  = idx >> 14;
    int n = ntg * 16 + (l & 15);
    int kappa = ks * 32 + (l >> 4) * 8 + j;
    int k = kappa >> 8, c = kappa & 255;
    const float* w = (n < 256) ? fw : zw;
    int h = n & 255;
    wfrag[idx] = f2bf(w[(h * C_ + c) * K_ + k]);
}

// ---------------------------------------------------------------------------
// Fused conv (f and z) + gates + per-chunk affine scan.
// Block: 64 t rows x 256 h. 8 waves; wave wv owns h in [wv*32, wv*32+32):
//   ni 0,1 -> f cols (ntg = wv*2+ni), ni 2,3 -> z cols (ntg = 16+wv*2+ni-2).
// ks-loop: R4's rolled 24-iter structure (measured best) + ping-pong register
// prefetch of B fragments (bload(ks+1) issued before conv_step(ks)).
// Two-phase epilogue keeps LDS at 33792 B.
// ---------------------------------------------------------------------------
__device__ __forceinline__ void bload(const ushort* wb, int ks, const int (&ntg)[4],
                                      bf16x8 (&dst)[4]) {
#pragma unroll
    for (int ni = 0; ni < 4; ++ni)
        dst[ni] = *(const bf16x8*)(wb + (size_t)ks * 16384 + (size_t)ntg[ni] * 512);
}

__device__ __forceinline__ void conv_step(const char* smem, int ks, int lr, int lg,
                                          const bf16x8 (&bfr)[4], f32x4 (&acc)[4][4]) {
    const int k = ks >> 3;
    const int cb = ((ks & 7) * 32 + lg * 8) * 2;
    bf16x8 afr[4];
#pragma unroll
    for (int mi = 0; mi < 4; ++mi) {
        int row = mi * 16 + lr + k;
        afr[mi] = *(const bf16x8*)(smem + row * 512 + (cb ^ ((row & 7) << 4)));
    }
#pragma unroll
    for (int ni = 0; ni < 4; ++ni)
#pragma unroll
        for (int mi = 0; mi < 4; ++mi)
            acc[mi][ni] = __builtin_amdgcn_mfma_f32_16x16x32_bf16(afr[mi], bfr[ni], acc[mi][ni], 0, 0, 0);
}

template <int P>
__device__ __forceinline__ void epi_write(f32x4 (&acc)[4][4], unsigned* buf,
                                          int lr, int lg, int h0) {
#pragma unroll
    for (int m2 = 0; m2 < 2; ++m2) {
        const int mi = 2 * P + m2;
#pragma unroll
        for (int ni = 0; ni < 2; ++ni) {
            const int h = h0 + ni * 16 + lr;
#pragma unroll
            for (int r = 0; r < 4; ++r) {
                float fv = sigm(acc[mi][ni][r]);
                float av = sigm(acc[mi][ni + 2][r]) * (1.0f - fv);
                int tl = m2 * 16 + lg * 4 + r;
                buf[tl * 256 + (h ^ ((tl << 2) & 31))] =
                    (unsigned)f2bf(av) | ((unsigned)f2bf(fv) << 16);
            }
        }
    }
}

template <int P>
__device__ __forceinline__ void chunk_scan(const unsigned* buf, int b, int bx, int tid,
                                           unsigned* AP, unsigned* APl, float* fl) {
    if (tid < 256) {
        const int h = tid;
        const int chunk = bx * 2 + P;
        const int r0 = chunk * TC;
        unsigned* app = AP + ((size_t)b * T_ + r0) * H_ + h;
        unsigned u = buf[h];
        float A = bf2f((ushort)(u & 0xffff));
        float Pp = 1.0f;
        float f_prev = bf2f((ushort)(u >> 16));
        unsigned upk = (unsigned)f2bf(A) | ((unsigned)f2bf(Pp) << 16);
        app[0] = upk;
#pragma unroll 8
        for (int j = 1; j < TC; ++j) {
            u = buf[j * 256 + (h ^ ((j << 2) & 31))];
            float a = bf2f((ushort)(u & 0xffff));
            float f = bf2f((ushort)(u >> 16));
            A = fmaf(f_prev, A, a);
            Pp *= f_prev;
            f_prev = f;
            upk = (unsigned)f2bf(A) | ((unsigned)f2bf(Pp) << 16);
            app[(size_t)j * H_] = upk;
        }
        APl[((size_t)b * NC + chunk) * H_ + h] = upk;
        fl[((size_t)b * NC + chunk) * H_ + h] = f_prev;
    }
}

__global__ __launch_bounds__(512, 4) void conv_scan_kernel(const float* __restrict__ x,
                                                           const ushort* __restrict__ wfrag,
                                                           const float* __restrict__ fb,
                                                           const float* __restrict__ zb,
                                                           unsigned* __restrict__ AP,
                                                           unsigned* __restrict__ APl,
                                                           float* __restrict__ fl) {
    __shared__ __align__(16) char smem[66 * 512];   // union: xs 66x512B | buf 32x256 uint
    unsigned* buf = (unsigned*)smem;

    const int b = blockIdx.y;
    const int t0 = blockIdx.x * 64;
    const int tid = threadIdx.x;

    // Stage x[b, t0-1 .. t0+64, :] as bf16, swizzled: byte = row*512 + ((2c) ^ ((row&7)<<4))
    for (int idx = tid; idx < 66 * 64; idx += 512) {
        int row = idx >> 6;
        int c4 = (idx & 63) * 4;
        int t = t0 - 1 + row;
        float4 v = make_float4(0.f, 0.f, 0.f, 0.f);
        if (t >= 0 && t < T_) v = *(const float4*)(x + ((size_t)(b * T_ + t)) * C_ + c4);
        ushort4 w4;
        w4.x = f2bf(v.x); w4.y = f2bf(v.y); w4.z = f2bf(v.z); w4.w = f2bf(v.w);
        *(ushort4*)(smem + row * 512 + ((c4 * 2) ^ ((row & 7) << 4))) = w4;
    }
    __syncthreads();

    const int wv = tid >> 6;
    const int l  = tid & 63;
    const int lr = l & 15;
    const int lg = l >> 4;
    const int h0 = wv * 32;

    f32x4 acc[4][4];
#pragma unroll
    for (int ni = 0; ni < 4; ++ni) {
        float bv = (ni < 2 ? fb : zb)[h0 + (ni & 1) * 16 + lr];
        f32x4 bvv = {bv, bv, bv, bv};
#pragma unroll
        for (int mi = 0; mi < 4; ++mi) acc[mi][ni] = bvv;
    }

    const ushort* wb = wfrag + (size_t)l * 8;
    int ntg_[4];
#pragma unroll
    for (int ni = 0; ni < 4; ++ni)
        ntg_[ni] = (ni < 2) ? (wv * 2 + ni) : (16 + wv * 2 + ni - 2);

    // Ping-pong prefetch: issue bload(ks+1) before conv_step(ks).
    bf16x8 ba[4], bb[4];
    bload(wb, 0, ntg_, ba);
#pragma unroll 1
    for (int ks = 0; ks < 24; ks += 2) {
        bload(wb, ks + 1, ntg_, bb);
        conv_step(smem, ks, lr, lg, ba, acc);
        if (ks + 2 < 24) bload(wb, ks + 2, ntg_, ba);
        conv_step(smem, ks + 1, lr, lg, bb, acc);
    }

    // ---- phase 0: chunk = bx*2 (mi 0,1) ----
    __syncthreads();                       // xs dead; buf aliases it
    epi_write<0>(acc, buf, lr, lg, h0);
    __syncthreads();
    chunk_scan<0>(buf, b, blockIdx.x, tid, AP, APl, fl);

    // ---- phase 1: chunk = bx*2+1 (mi 2,3) ----
    __syncthreads();
    epi_write<1>(acc, buf, lr, lg, h0);
    __syncthreads();
    chunk_scan<1>(buf, b, blockIdx.x, tid, AP, APl, fl);
}

// Per (b,h): serial over contiguous chunk summaries (coalesced, prefetchable).
// s~_c = fl(c-1)*s_c; s_{c+1} = A31 + P'31*s~_c.
__global__ __launch_bounds__(256) void combine_kernel(const unsigned* __restrict__ APl,
                                                      const float* __restrict__ fl,
                                                      const float* __restrict__ init_f,
                                                      const float* __restrict__ init_z,
                                                      float* __restrict__ out,
                                                      float* __restrict__ sin_) {
    const int b = blockIdx.x;
    const int h = threadIdx.x;
    float f0 = sigm(init_f[b * H_ + h]);
    float z0 = sigm(init_z[b * H_ + h]);
    float s = z0 * (1.0f - f0);
    out[(size_t)b * (T_ + 1) * H_ + h] = s;
    float flp = f0;
    const unsigned* ap = APl + (size_t)b * NC * H_ + h;
    const float* fp = fl + (size_t)b * NC * H_ + h;
    float* sp = sin_ + (size_t)b * NC * H_ + h;
#pragma unroll 8
    for (int c = 0; c < NC; ++c) {
        unsigned u = ap[(size_t)c * H_];
        float fln = fp[(size_t)c * H_];
        float st = flp * s;
        sp[(size_t)c * H_] = st;
        s = fmaf(bf2f((ushort)(u >> 16)), st, bf2f((ushort)(u & 0xffff)));
        flp = fln;
    }
}

// out_{r0+1+j} = A_j + P'_j * s~_c   (fully parallel, 4 h per thread)
__global__ __launch_bounds__(256) void apply_kernel(const unsigned* __restrict__ AP,
                                                    const float* __restrict__ sin_,
                                                    float* __restrict__ out) {
    const int c = blockIdx.x;
    const int b = blockIdx.y;
    const int tid = threadIdx.x;
    const int jr = tid >> 6;
    const int h4 = (tid & 63) * 4;
    const int r0 = c * TC;
    const float4 s4 = *(const float4*)(sin_ + ((size_t)b * NC + c) * H_ + h4);
#pragma unroll
    for (int p = 0; p < 8; ++p) {
        const int j = p * 4 + jr;
        const uint4 u4 = *(const uint4*)(AP + ((size_t)b * T_ + r0 + j) * H_ + h4);
        float4 o;
        o.x = fmaf(bf2f((ushort)(u4.x >> 16)), s4.x, bf2f((ushort)(u4.x & 0xffff)));
        o.y = fmaf(bf2f((ushort)(u4.y >> 16)), s4.y, bf2f((ushort)(u4.y & 0xffff)));
        o.z = fmaf(bf2f((ushort)(u4.z >> 16)), s4.z, bf2f((ushort)(u4.z & 0xffff)));
        o.w = fmaf(bf2f((ushort)(u4.w >> 16)), s4.w, bf2f((ushort)(u4.w & 0xffff)));
        *(float4*)(out + ((size_t)b * (T_ + 1) + r0 + 1 + j) * H_ + h4) = o;
    }
}

extern "C" void kernel_launch(void* const* d_in, const int* in_sizes, int n_in,
                              void* d_out, int out_size, void* d_ws, size_t ws_size,
                              hipStream_t stream) {
    const float* inputs = (const float*)d_in[0];   // [B,T,C]
    const float* init_f = (const float*)d_in[1];   // [B,H]
    const float* init_z = (const float*)d_in[2];   // [B,H]
    const float* f_w    = (const float*)d_in[3];   // [H,C,K]
    const float* f_b    = (const float*)d_in[4];   // [H]
    const float* z_w    = (const float*)d_in[5];   // [H,C,K]
    const float* z_b    = (const float*)d_in[6];   // [H]
    float* out = (float*)d_out;                    // [B,T+1,H]

    // ws: wfrag 768KB | AP (B*T*H uint, 32MB) | APl 1MB | fl 1MB | sin 1MB
    ushort* wfrag = (ushort*)d_ws;
    unsigned* AP  = (unsigned*)(wfrag + WFRAG_ELEMS);
    unsigned* APl = AP + (size_t)B_ * T_ * H_;
    float* fl     = (float*)(APl + (size_t)B_ * NC * H_);
    float* sin_   = fl + (size_t)B_ * NC * H_;

    wfrag_kernel<<<(WFRAG_ELEMS + 255) / 256, 256, 0, stream>>>(f_w, z_w, wfrag);

    dim3 cgrid(T_ / 64, B_, 1);
    conv_scan_kernel<<<cgrid, 512, 0, stream>>>(inputs, wfrag, f_b, z_b, AP, APl, fl);

    combine_kernel<<<B_, H_, 0, stream>>>(APl, fl, init_f, init_z, out, sin_);

    dim3 agrid(NC, B_, 1);
    apply_kernel<<<agrid, 256, 0, stream>>>(AP, sin_, out);
}

// Round 9
// 66.192 us; speedup vs baseline: 1.2251x; 1.0401x over previous
//
#include <hip/hip_runtime.h>
#include <hip/hip_bf16.h>

#define B_ 8
#define T_ 4096
#define C_ 256
#define H_ 256
#define K_ 3
#define NC 128          // time chunks (32 t each)
#define TC 32
#define WFRAG_ELEMS (24 * 32 * 64 * 8)   // [ks][ntg][lane][j] bf16

typedef __attribute__((ext_vector_type(8))) __bf16 bf16x8;
typedef __attribute__((ext_vector_type(4))) float f32x4;

__device__ __forceinline__ float sigm(float x) { return 1.0f / (1.0f + __expf(-x)); }

__device__ __forceinline__ ushort f2bf(float f) {
    union { float f; unsigned u; } v; v.f = f;
    return (ushort)((v.u + 0x7FFFu + ((v.u >> 16) & 1u)) >> 16);
}
__device__ __forceinline__ float bf2f(ushort u) {
    union { unsigned u; float f; } v; v.u = ((unsigned)u) << 16; return v.f;
}
// 1-instr pack: low16 = bf16(lo), high16 = bf16(hi)  [RNE, same as f2bf]
__device__ __forceinline__ unsigned cvt_pk_bf16(float lo, float hi) {
    unsigned r;
    asm("v_cvt_pk_bf16_f32 %0, %1, %2" : "=v"(r) : "v"(lo), "v"(hi));
    return r;
}

// Gather f_w,z_w into B-fragment-linear bf16 layout for mfma_f32_16x16x32_bf16.
// n = ntg*16 + (l&15)  (n<256 -> f[h=n], else z[h=n-256]);  kappa = ks*32 + (l>>4)*8 + j = k*256 + c.
__global__ __launch_bounds__(256) void wfrag_kernel(const float* __restrict__ fw,
                                                    const float* __restrict__ zw,
                                                    ushort* __restrict__ wfrag) {
    int idx = blockIdx.x * 256 + threadIdx.x;
    if (idx >= WFRAG_ELEMS) return;
    int j   = idx & 7;
    int l   = (idx >> 3) & 63;
    int ntg = (idx >> 9) & 31;
    int ks  = idx >> 14;
    int n = ntg * 16 + (l & 15);
    int kappa = ks * 32 + (l >> 4) * 8 + j;
    int k = kappa >> 8, c = kappa & 255;
    const float* w = (n < 256) ? fw : zw;
    int h = n & 255;
    wfrag[idx] = f2bf(w[(h * C_ + c) * K_ + k]);
}

// ---------------------------------------------------------------------------
// Fused conv (f and z) + gates + per-chunk affine scan.
// Block: 64 t rows x 256 h. 8 waves; wave wv owns h in [wv*32, wv*32+32):
//   ni 0,1 -> f cols (ntg = wv*2+ni), ni 2,3 -> z cols (ntg = 16+wv*2+ni-2).
// ks-loop: R4/R8 rolled structure + ping-pong B prefetch (measured best).
// One-phase epilogue: both chunks packed to 64x256 LDS (cvt_pk), then a
// 512-thread scan (tid>>8 = chunk, tid&255 = h).
// ---------------------------------------------------------------------------
__device__ __forceinline__ void bload(const ushort* wb, int ks, const int (&ntg)[4],
                                      bf16x8 (&dst)[4]) {
#pragma unroll
    for (int ni = 0; ni < 4; ++ni)
        dst[ni] = *(const bf16x8*)(wb + (size_t)ks * 16384 + (size_t)ntg[ni] * 512);
}

__device__ __forceinline__ void conv_step(const char* smem, int ks, int lr, int lg,
                                          const bf16x8 (&bfr)[4], f32x4 (&acc)[4][4]) {
    const int k = ks >> 3;
    const int cb = ((ks & 7) * 32 + lg * 8) * 2;
    bf16x8 afr[4];
#pragma unroll
    for (int mi = 0; mi < 4; ++mi) {
        int row = mi * 16 + lr + k;
        afr[mi] = *(const bf16x8*)(smem + row * 512 + (cb ^ ((row & 7) << 4)));
    }
#pragma unroll
    for (int ni = 0; ni < 4; ++ni)
#pragma unroll
        for (int mi = 0; mi < 4; ++mi)
            acc[mi][ni] = __builtin_amdgcn_mfma_f32_16x16x32_bf16(afr[mi], bfr[ni], acc[mi][ni], 0, 0, 0);
}

__global__ __launch_bounds__(512, 4) void conv_scan_kernel(const float* __restrict__ x,
                                                           const ushort* __restrict__ wfrag,
                                                           const float* __restrict__ fb,
                                                           const float* __restrict__ zb,
                                                           unsigned* __restrict__ AP,
                                                           unsigned* __restrict__ APl,
                                                           float* __restrict__ fl) {
    __shared__ __align__(16) char smem[65536];   // union: xs 66x512B | buf 64x256 uint
    unsigned* buf = (unsigned*)smem;

    const int b = blockIdx.y;
    const int t0 = blockIdx.x * 64;
    const int tid = threadIdx.x;

    // Stage x[b, t0-1 .. t0+64, :] as bf16, swizzled: byte = row*512 + ((2c) ^ ((row&7)<<4))
    if (blockIdx.x == 0 || blockIdx.x == gridDim.x - 1) {
        for (int idx = tid; idx < 66 * 64; idx += 512) {
            int row = idx >> 6;
            int c4 = (idx & 63) * 4;
            int t = t0 - 1 + row;
            float4 v = make_float4(0.f, 0.f, 0.f, 0.f);
            if (t >= 0 && t < T_) v = *(const float4*)(x + ((size_t)(b * T_ + t)) * C_ + c4);
            uint2 w2 = make_uint2(cvt_pk_bf16(v.x, v.y), cvt_pk_bf16(v.z, v.w));
            *(uint2*)(smem + row * 512 + ((c4 * 2) ^ ((row & 7) << 4))) = w2;
        }
    } else {
        for (int idx = tid; idx < 66 * 64; idx += 512) {
            int row = idx >> 6;
            int c4 = (idx & 63) * 4;
            int t = t0 - 1 + row;
            float4 v = *(const float4*)(x + ((size_t)(b * T_ + t)) * C_ + c4);
            uint2 w2 = make_uint2(cvt_pk_bf16(v.x, v.y), cvt_pk_bf16(v.z, v.w));
            *(uint2*)(smem + row * 512 + ((c4 * 2) ^ ((row & 7) << 4))) = w2;
        }
    }
    __syncthreads();

    const int wv = tid >> 6;
    const int l  = tid & 63;
    const int lr = l & 15;
    const int lg = l >> 4;
    const int h0 = wv * 32;

    f32x4 acc[4][4];
#pragma unroll
    for (int ni = 0; ni < 4; ++ni) {
        float bv = (ni < 2 ? fb : zb)[h0 + (ni & 1) * 16 + lr];
        f32x4 bvv = {bv, bv, bv, bv};
#pragma unroll
        for (int mi = 0; mi < 4; ++mi) acc[mi][ni] = bvv;
    }

    const ushort* wb = wfrag + (size_t)l * 8;
    int ntg_[4];
#pragma unroll
    for (int ni = 0; ni < 4; ++ni)
        ntg_[ni] = (ni < 2) ? (wv * 2 + ni) : (16 + wv * 2 + ni - 2);

    // Ping-pong prefetch: issue bload(ks+1) before conv_step(ks).
    bf16x8 ba[4], bb[4];
    bload(wb, 0, ntg_, ba);
#pragma unroll 1
    for (int ks = 0; ks < 24; ks += 2) {
        bload(wb, ks + 1, ntg_, bb);
        conv_step(smem, ks, lr, lg, ba, acc);
        if (ks + 2 < 24) bload(wb, ks + 2, ntg_, ba);
        conv_step(smem, ks + 1, lr, lg, bb, acc);
    }

    // One-phase epilogue: sigmoid + pack {a,f} for BOTH chunks into buf[64][256].
    __syncthreads();                       // xs dead; buf aliases it
#pragma unroll
    for (int mi = 0; mi < 4; ++mi) {
#pragma unroll
        for (int ni = 0; ni < 2; ++ni) {
            const int h = h0 + ni * 16 + lr;
#pragma unroll
            for (int r = 0; r < 4; ++r) {
                float fv = sigm(acc[mi][ni][r]);
                float av = sigm(acc[mi][ni + 2][r]) * (1.0f - fv);
                int tl = (mi & 1) * 16 + lg * 4 + r;          // t within chunk
                int trow = (mi >> 1) * 32 + tl;               // buf row
                buf[trow * 256 + (h ^ ((tl << 2) & 31))] = cvt_pk_bf16(av, fv);
            }
        }
    }
    __syncthreads();

    // Parallel per-chunk scan: all 512 threads (ch = tid>>8, h = tid&255).
    {
        const int ch = tid >> 8;
        const int h = tid & 255;
        const int chunk = blockIdx.x * 2 + ch;
        const int r0 = chunk * TC;
        const unsigned* bp = buf + ch * 32 * 256;
        unsigned* app = AP + ((size_t)b * T_ + r0) * H_ + h;
        unsigned u = bp[h];
        float A = bf2f((ushort)(u & 0xffff));
        float Pp = 1.0f;
        float f_prev = bf2f((ushort)(u >> 16));
        unsigned upk = cvt_pk_bf16(A, Pp);
        app[0] = upk;
#pragma unroll 8
        for (int j = 1; j < TC; ++j) {
            u = bp[j * 256 + (h ^ ((j << 2) & 31))];
            float a = bf2f((ushort)(u & 0xffff));
            float f = bf2f((ushort)(u >> 16));
            A = fmaf(f_prev, A, a);
            Pp *= f_prev;
            f_prev = f;
            upk = cvt_pk_bf16(A, Pp);
            app[(size_t)j * H_] = upk;
        }
        APl[((size_t)b * NC + chunk) * H_ + h] = upk;        // contiguous summary
        fl[((size_t)b * NC + chunk) * H_ + h] = f_prev;
    }
}

// Per (b,h): serial over contiguous chunk summaries (coalesced, prefetchable).
// s~_c = fl(c-1)*s_c; s_{c+1} = A31 + P'31*s~_c.
__global__ __launch_bounds__(256) void combine_kernel(const unsigned* __restrict__ APl,
                                                      const float* __restrict__ fl,
                                                      const float* __restrict__ init_f,
                                                      const float* __restrict__ init_z,
                                                      float* __restrict__ out,
                                                      float* __restrict__ sin_) {
    const int b = blockIdx.x;
    const int h = threadIdx.x;
    float f0 = sigm(init_f[b * H_ + h]);
    float z0 = sigm(init_z[b * H_ + h]);
    float s = z0 * (1.0f - f0);
    out[(size_t)b * (T_ + 1) * H_ + h] = s;
    float flp = f0;
    const unsigned* ap = APl + (size_t)b * NC * H_ + h;
    const float* fp = fl + (size_t)b * NC * H_ + h;
    float* sp = sin_ + (size_t)b * NC * H_ + h;
#pragma unroll 8
    for (int c = 0; c < NC; ++c) {
        unsigned u = ap[(size_t)c * H_];
        float fln = fp[(size_t)c * H_];
        float st = flp * s;
        sp[(size_t)c * H_] = st;
        s = fmaf(bf2f((ushort)(u >> 16)), st, bf2f((ushort)(u & 0xffff)));
        flp = fln;
    }
}

// out_{r0+1+j} = A_j + P'_j * s~_c   (fully parallel, 4 h per thread)
__global__ __launch_bounds__(256) void apply_kernel(const unsigned* __restrict__ AP,
                                                    const float* __restrict__ sin_,
                                                    float* __restrict__ out) {
    const int c = blockIdx.x;
    const int b = blockIdx.y;
    const int tid = threadIdx.x;
    const int jr = tid >> 6;
    const int h4 = (tid & 63) * 4;
    const int r0 = c * TC;
    const float4 s4 = *(const float4*)(sin_ + ((size_t)b * NC + c) * H_ + h4);
#pragma unroll
    for (int p = 0; p < 8; ++p) {
        const int j = p * 4 + jr;
        const uint4 u4 = *(const uint4*)(AP + ((size_t)b * T_ + r0 + j) * H_ + h4);
        float4 o;
        o.x = fmaf(bf2f((ushort)(u4.x >> 16)), s4.x, bf2f((ushort)(u4.x & 0xffff)));
        o.y = fmaf(bf2f((ushort)(u4.y >> 16)), s4.y, bf2f((ushort)(u4.y & 0xffff)));
        o.z = fmaf(bf2f((ushort)(u4.z >> 16)), s4.z, bf2f((ushort)(u4.z & 0xffff)));
        o.w = fmaf(bf2f((ushort)(u4.w >> 16)), s4.w, bf2f((ushort)(u4.w & 0xffff)));
        *(float4*)(out + ((size_t)b * (T_ + 1) + r0 + 1 + j) * H_ + h4) = o;
    }
}

extern "C" void kernel_launch(void* const* d_in, const int* in_sizes, int n_in,
                              void* d_out, int out_size, void* d_ws, size_t ws_size,
                              hipStream_t stream) {
    const float* inputs = (const float*)d_in[0];   // [B,T,C]
    const float* init_f = (const float*)d_in[1];   // [B,H]
    const float* init_z = (const float*)d_in[2];   // [B,H]
    const float* f_w    = (const float*)d_in[3];   // [H,C,K]
    const float* f_b    = (const float*)d_in[4];   // [H]
    const float* z_w    = (const float*)d_in[5];   // [H,C,K]
    const float* z_b    = (const float*)d_in[6];   // [H]
    float* out = (float*)d_out;                    // [B,T+1,H]

    // ws: wfrag 768KB | AP (B*T*H uint, 32MB) | APl 1MB | fl 1MB | sin 1MB
    ushort* wfrag = (ushort*)d_ws;
    unsigned* AP  = (unsigned*)(wfrag + WFRAG_ELEMS);
    unsigned* APl = AP + (size_t)B_ * T_ * H_;
    float* fl     = (float*)(APl + (size_t)B_ * NC * H_);
    float* sin_   = fl + (size_t)B_ * NC * H_;

    wfrag_kernel<<<(WFRAG_ELEMS + 255) / 256, 256, 0, stream>>>(f_w, z_w, wfrag);

    dim3 cgrid(T_ / 64, B_, 1);
    conv_scan_kernel<<<cgrid, 512, 0, stream>>>(inputs, wfrag, f_b, z_b, AP, APl, fl);

    combine_kernel<<<B_, H_, 0, stream>>>(APl, fl, init_f, init_z, out, sin_);

    dim3 agrid(NC, B_, 1);
    apply_kernel<<<agrid, 256, 0, stream>>>(AP, sin_, out);
}